// Round 8
// baseline (155.564 us; speedup 1.0000x reference)
//
#include <hip/hip_runtime.h>
#include <hip/hip_cooperative_groups.h>

#define HH 128
#define WW 128
#define HWSZ (HH * WW)
#define CC 64
#define OO 64
#define BB 4
#define NOFF 18
#define KK 576          // C*9
#define EPS 1e-5f

// ws layout (dword offsets)
#define WS_BG     0                         // 72*64*4 = 18432 (deform weights, quad-packed)
#define WS_BGO    18432                     // 72*32*4 = 9216  (offset weights, quad-packed, N=32)
#define WS_SUMS   27648                     // 64
#define WS_SUMSQ  27712                     // 64
#define WS_YBUF   27776                     // 4*64*16384 (fallback path only)

typedef __attribute__((ext_vector_type(8))) short short8;
typedef __attribute__((ext_vector_type(4))) int int4v;
typedef __attribute__((ext_vector_type(4))) float f32x4;

struct SM {
  union {
    struct {
      int A[4 * 16 * 100];      // 25.6 KB im2col tiles (+ stats alias)
      int M[4 * 144 * 4];       // 9.2 KB bilinear meta
      float offL[4][NOFF][16];  // 4.6 KB offsets
    } c;
    float T[CC][WW + 1];        // 33 KB transpose tile
  };
};                               // union = 39424 B -> 4 blocks/CU

__device__ inline unsigned bf16rne(float f) {
  unsigned u = __float_as_uint(f);
  u += 0x7fff + ((u >> 16) & 1);
  return u >> 16;
}

// ---- stage A: NHWC-bf16 transpose (bid<512) + weight repack + stats zero ----
__device__ void stage_prep(const float* __restrict__ x,
                           const float* __restrict__ off_w,
                           const float* __restrict__ dc_w,
                           unsigned int* __restrict__ xTu,
                           int* __restrict__ Bg, int* __restrict__ Bgo,
                           float* __restrict__ sums, SM& sm, int bid, int tid) {
  if (bid < BB * HH) {
    int b = bid >> 7, h = bid & 127;
    int tw = tid & 127, th = tid >> 7;
    const float* xp = x + (size_t)b * CC * HWSZ + h * WW;
#pragma unroll 8
    for (int i = 0; i < 32; ++i) {
      int c = i * 2 + th;
      sm.T[c][tw] = xp[c * HWSZ + tw];
    }
    __syncthreads();
    int c2 = tid & 31, wq = tid >> 5;
    unsigned int* op = xTu + ((size_t)(b * HH + h) * WW) * 32;
#pragma unroll 8
    for (int i = 0; i < 16; ++i) {
      int w = i * 8 + wq;
      unsigned pk = bf16rne(sm.T[2 * c2][w]) | (bf16rne(sm.T[2 * c2 + 1][w]) << 16);
      op[w * 32 + c2] = pk;
    }
  } else if (bid < BB * HH + 64) {
    int t0 = (bid - BB * HH) * 256 + tid;
    const int stride = 64 * 256;
    for (int i = t0; i < 72 * 64 * 4; i += stride) {
      int j = i & 3, o = (i >> 2) & 63, g = i >> 8;
      int k2 = g * 4 + j, t = k2 >> 5, jj = k2 & 31;
      unsigned lo = bf16rne(dc_w[o * KK + (2 * jj) * 9 + t]);
      unsigned hi = bf16rne(dc_w[o * KK + (2 * jj + 1) * 9 + t]);
      Bg[i] = (int)(lo | (hi << 16));
    }
    for (int i = t0; i < 72 * 32 * 4; i += stride) {
      int j = i & 3, o = (i >> 2) & 31, g = i >> 7;
      int k2 = g * 4 + j, t = k2 >> 5, jj = k2 & 31;
      unsigned pk = 0;
      if (o < NOFF) {
        unsigned lo = bf16rne(off_w[o * KK + (2 * jj) * 9 + t]);
        unsigned hi = bf16rne(off_w[o * KK + (2 * jj + 1) * 9 + t]);
        pk = lo | (hi << 16);
      }
      Bgo[i] = (int)pk;
    }
    if (t0 < 128)
      __hip_atomic_store(&sums[t0], 0.0f, __ATOMIC_RELAXED, __HIP_MEMORY_SCOPE_AGENT);
  }
}

// ---- stage B: fused offset-conv + deform-conv + BN stats; acc stays live ----
__device__ void stage_conv(const unsigned int* __restrict__ xTu,
                           const int* __restrict__ Bg, const int* __restrict__ Bgo,
                           const float* __restrict__ off_b,
                           const float* __restrict__ dc_b,
                           float* __restrict__ sums, float* __restrict__ sumsq,
                           float* __restrict__ ybuf, SM& sm, int bid, int tid,
                           f32x4 (&acc)[4]) {
  int cg = tid >> 6, lane = tid & 63;
  int b = bid >> 8, rem = bid & 255;
  int h = rem >> 1, w0 = (rem & 1) * 64;
  int hw0 = h * WW + w0;
  int p0 = cg * 16;
  int n16 = lane & 15, q = lane >> 4;
  int pg = lane >> 3, part = lane & 7;
  const unsigned int* xbu = xTu + (size_t)b * HWSZ * 32;

  // phase 1: offset conv (im2col copy + MFMA), chunk order staggered per wave
  f32x4 acc2[2] = {f32x4{0, 0, 0, 0}, f32x4{0, 0, 0, 0}};
#pragma unroll 1
  for (int cc = 0; cc < 3; ++cc) {
    int chunk = cc + cg;
    chunk = (chunk >= 3) ? chunk - 3 : chunk;
    chunk = (chunk >= 3) ? chunk - 3 : chunk;
    int cy = h + chunk - 1;
    bool vy = (cy >= 0) && (cy < HH);
    int cys = min(max(cy, 0), HH - 1);
#pragma unroll
    for (int tl = 0; tl < 3; ++tl) {
#pragma unroll
      for (int i = 0; i < 2; ++i) {
        int px = i * 8 + pg;
        int cx = w0 + p0 + px + tl - 1;
        bool v = vy && (cx >= 0) && (cx < WW);
        int cxs = min(max(cx, 0), WW - 1);
        int4v val = *(const int4v*)&xbu[(cys * WW + cxs) * 32 + part * 4];
        if (!v) { val.x = 0; val.y = 0; val.z = 0; val.w = 0; }
        *(int4v*)&sm.c.A[(p0 + px) * 100 + tl * 32 + part * 4] = val;
      }
    }
#pragma unroll 1
    for (int kk = 0; kk < 6; ++kk) {
      int4v av = *(const int4v*)&sm.c.A[(p0 + n16) * 100 + kk * 16 + q * 4];
      short8 af = __builtin_bit_cast(short8, av);
      int g = chunk * 24 + kk * 4 + q;
#pragma unroll
      for (int nt = 0; nt < 2; ++nt) {
        int4v bv = *(const int4v*)&Bgo[(g * 32 + nt * 16 + n16) * 4];
        short8 bfr = __builtin_bit_cast(short8, bv);
        acc2[nt] = __builtin_amdgcn_mfma_f32_16x16x32_bf16(af, bfr, acc2[nt], 0, 0, 0);
      }
    }
  }
#pragma unroll
  for (int nt = 0; nt < 2; ++nt) {
    int o = nt * 16 + n16;
    if (o < NOFF) {
      float bv = off_b[o];
#pragma unroll
      for (int r = 0; r < 4; ++r) sm.c.offL[cg][o][q * 4 + r] = acc2[nt][r] + bv;
    }
  }

  // phase 2: bilinear meta (wave-private)
  int* Mw = sm.c.M + cg * 144 * 4;
#pragma unroll
  for (int it = 0; it < 3; ++it) {
    int m = it * 64 + lane;
    if (m < 144) {
      int pxl = (unsigned)m / 9u;
      int t = m - pxl * 9;
      float dy = sm.c.offL[cg][2 * t][pxl];
      float dx = sm.c.offL[cg][2 * t + 1][pxl];
      float py = (float)(h + t / 3 - 1) + dy;
      float pxf = (float)(w0 + p0 + pxl + (t % 3) - 1) + dx;
      float fy0 = floorf(py), fx0 = floorf(pxf);
      float ay = py - fy0, ax = pxf - fx0;
      int iy0 = (int)fy0, ix0 = (int)fx0;
      int iy1 = iy0 + 1, ix1 = ix0 + 1;
      float wy0 = 1.0f - ay, wy1 = ay, wx0 = 1.0f - ax, wx1 = ax;
      if (!(iy0 >= 0 && iy0 < HH)) wy0 = 0.0f;
      if (!(iy1 >= 0 && iy1 < HH)) wy1 = 0.0f;
      if (!(ix0 >= 0 && ix0 < WW)) wx0 = 0.0f;
      if (!(ix1 >= 0 && ix1 < WW)) wx1 = 0.0f;
      int cy0 = min(max(iy0, 0), HH - 1), cy1 = min(max(iy1, 0), HH - 1);
      int cx0 = min(max(ix0, 0), WW - 1), cx1 = min(max(ix1, 0), WW - 1);
      int4v mv;
      mv.x = (cy0 * WW + cx0) | ((cy0 * WW + cx1) << 16);
      mv.y = (cy1 * WW + cx0) | ((cy1 * WW + cx1) << 16);
      mv.z = (int)(bf16rne(wy0 * wx0) | (bf16rne(wy0 * wx1) << 16));
      mv.w = (int)(bf16rne(wy1 * wx0) | (bf16rne(wy1 * wx1) << 16));
      *(int4v*)&Mw[m * 4] = mv;
    }
  }

  // phase 3: pair-gather + MFMA, staggered chunks
  int p = lane >> 5;
  int c2 = lane & 31;
#pragma unroll
  for (int nt = 0; nt < 4; ++nt) acc[nt] = f32x4{0, 0, 0, 0};
#pragma unroll 1
  for (int cc = 0; cc < 3; ++cc) {
    int chunk = cc + cg;
    chunk = (chunk >= 3) ? chunk - 3 : chunk;
    chunk = (chunk >= 3) ? chunk - 3 : chunk;
#pragma unroll 1
    for (int tl = 0; tl < 3; ++tl) {
#pragma unroll 4
      for (int pp = 0; pp < 16; pp += 2) {
        int pxl = pp + p;
        int4v mv = *(const int4v*)&Mw[(pxl * 9 + chunk * 3 + tl) * 4];
        unsigned o00 = mv.x & 0xffff, o01 = ((unsigned)mv.x) >> 16;
        unsigned o10 = mv.y & 0xffff, o11 = ((unsigned)mv.y) >> 16;
        unsigned d00 = xbu[o00 * 32 + c2];
        unsigned d01 = xbu[o01 * 32 + c2];
        unsigned d10 = xbu[o10 * 32 + c2];
        unsigned d11 = xbu[o11 * 32 + c2];
        float w00 = __uint_as_float(((unsigned)mv.z) << 16);
        float w01 = __uint_as_float(((unsigned)mv.z) & 0xffff0000u);
        float w10 = __uint_as_float(((unsigned)mv.w) << 16);
        float w11 = __uint_as_float(((unsigned)mv.w) & 0xffff0000u);
        float slo = w00 * __uint_as_float(d00 << 16);
        slo = fmaf(w01, __uint_as_float(d01 << 16), slo);
        slo = fmaf(w10, __uint_as_float(d10 << 16), slo);
        slo = fmaf(w11, __uint_as_float(d11 << 16), slo);
        float shi = w00 * __uint_as_float(d00 & 0xffff0000u);
        shi = fmaf(w01, __uint_as_float(d01 & 0xffff0000u), shi);
        shi = fmaf(w10, __uint_as_float(d10 & 0xffff0000u), shi);
        shi = fmaf(w11, __uint_as_float(d11 & 0xffff0000u), shi);
        unsigned pk = __builtin_amdgcn_perm(
            __float_as_uint(shi) + 0x8000u,
            __float_as_uint(slo) + 0x8000u, 0x07060302u);
        sm.c.A[(p0 + pxl) * 100 + tl * 32 + c2] = (int)pk;
      }
    }
#pragma unroll 1
    for (int kk = 0; kk < 6; ++kk) {
      int4v av = *(const int4v*)&sm.c.A[(p0 + n16) * 100 + kk * 16 + q * 4];
      short8 af = __builtin_bit_cast(short8, av);
      int g = chunk * 24 + kk * 4 + q;
#pragma unroll
      for (int nt = 0; nt < 4; ++nt) {
        int4v bv = *(const int4v*)&Bg[(g * 64 + nt * 16 + n16) * 4];
        short8 bfr = __builtin_bit_cast(short8, bv);
        acc[nt] = __builtin_amdgcn_mfma_f32_16x16x32_bf16(af, bfr, acc[nt], 0, 0, 0);
      }
    }
  }

  // epilogue: add bias into acc, stats reduce (+optional ybuf store for fallback)
  float* SW = (float*)&sm.c.A[cg * 1600];
#pragma unroll
  for (int nt = 0; nt < 4; ++nt) {
    int o = nt * 16 + n16;
    float bv = dc_b[o];
    float s = 0.0f, ss = 0.0f;
#pragma unroll
    for (int r0 = 0; r0 < 4; ++r0) {
      acc[nt][r0] += bv;
      s += acc[nt][r0];
      ss += acc[nt][r0] * acc[nt][r0];
    }
    if (ybuf)
      *(f32x4*)(ybuf + (size_t)(b * OO + o) * HWSZ + hw0 + p0 + q * 4) = acc[nt];
    s += __shfl_xor(s, 16);  s += __shfl_xor(s, 32);
    ss += __shfl_xor(ss, 16); ss += __shfl_xor(ss, 32);
    if (lane < 16) {
      SW[nt * 16 + lane] = s;
      SW[64 + nt * 16 + lane] = ss;
    }
  }
  __syncthreads();
  if (tid < 64) {
    float ts = 0.0f, tq = 0.0f;
#pragma unroll
    for (int wv = 0; wv < 4; ++wv) {
      const float* Sv = (const float*)&sm.c.A[wv * 1600];
      ts += Sv[tid];
      tq += Sv[64 + tid];
    }
    atomicAdd(&sums[tid], ts);
    atomicAdd(&sumsq[tid], tq);
  }
}

// ---- stage C: normalize from registers, write out ----
__device__ void stage_norm(int bid, int tid, const f32x4 (&acc)[4],
                           const float* __restrict__ sums,
                           const float* __restrict__ sumsq,
                           const float* __restrict__ gamma,
                           const float* __restrict__ beta,
                           float* __restrict__ out) {
  int cg = tid >> 6, lane = tid & 63;
  int b = bid >> 8, rem = bid & 255;
  int h = rem >> 1, w0 = (rem & 1) * 64;
  int hw0 = h * WW + w0;
  int p0 = cg * 16;
  int n16 = lane & 15, q = lane >> 4;
  const float invN = 1.0f / (float)(BB * HWSZ);
#pragma unroll
  for (int nt = 0; nt < 4; ++nt) {
    int o = nt * 16 + n16;
    float sv = __hip_atomic_load(&sums[o], __ATOMIC_RELAXED, __HIP_MEMORY_SCOPE_AGENT);
    float qv = __hip_atomic_load(&sumsq[o], __ATOMIC_RELAXED, __HIP_MEMORY_SCOPE_AGENT);
    float mean = sv * invN;
    float var = qv * invN - mean * mean;
    float rstd = rsqrtf(var + EPS);
    float g = gamma[o] * rstd;
    float bta = beta[o] - mean * g;
    f32x4 r;
#pragma unroll
    for (int r0 = 0; r0 < 4; ++r0) r[r0] = fmaxf(acc[nt][r0] * g + bta, 0.0f);
    *(f32x4*)(out + (size_t)(b * OO + o) * HWSZ + hw0 + p0 + q * 4) = r;
  }
}

// ---- single cooperative kernel ----
__global__ __launch_bounds__(256) void coop_kernel(
    const float* __restrict__ x, const float* __restrict__ off_w,
    const float* __restrict__ dc_w, const float* __restrict__ off_b,
    const float* __restrict__ dc_b, const float* __restrict__ gamma,
    const float* __restrict__ beta, unsigned int* __restrict__ xTu,
    int* __restrict__ Bg, int* __restrict__ Bgo, float* __restrict__ sums,
    float* __restrict__ sumsq, float* __restrict__ out) {
  __shared__ SM sm;
  int bid = blockIdx.x, tid = threadIdx.x;
  stage_prep(x, off_w, dc_w, xTu, Bg, Bgo, sums, sm, bid, tid);
  cooperative_groups::this_grid().sync();
  f32x4 acc[4];
  stage_conv(xTu, Bg, Bgo, off_b, dc_b, sums, sumsq, nullptr, sm, bid, tid, acc);
  cooperative_groups::this_grid().sync();
  stage_norm(bid, tid, acc, sums, sumsq, gamma, beta, out);
}

// ---- fallback 3-kernel path (used if co-residency check fails) ----
__global__ __launch_bounds__(256) void prep_kernel(
    const float* __restrict__ x, const float* __restrict__ off_w,
    const float* __restrict__ dc_w, unsigned int* __restrict__ xTu,
    int* __restrict__ Bg, int* __restrict__ Bgo, float* __restrict__ sums) {
  __shared__ SM sm;
  stage_prep(x, off_w, dc_w, xTu, Bg, Bgo, sums, sm, blockIdx.x, threadIdx.x);
}

__global__ __launch_bounds__(256) void conv_kernel(
    const unsigned int* __restrict__ xTu, const int* __restrict__ Bg,
    const int* __restrict__ Bgo, const float* __restrict__ off_b,
    const float* __restrict__ dc_b, float* __restrict__ ybuf,
    float* __restrict__ sums, float* __restrict__ sumsq) {
  __shared__ SM sm;
  f32x4 acc[4];
  stage_conv(xTu, Bg, Bgo, off_b, dc_b, sums, sumsq, ybuf, sm, blockIdx.x,
             threadIdx.x, acc);
}

__global__ __launch_bounds__(256) void norm_kernel(
    const float* __restrict__ ybuf, const float* __restrict__ sums,
    const float* __restrict__ sumsq, const float* __restrict__ gamma,
    const float* __restrict__ beta, float* __restrict__ out) {
  int gid = blockIdx.x * 256 + threadIdx.x;
  int flat = gid << 2;
  int o = (flat >> 14) & 63;
  const float invN = 1.0f / (float)(BB * HWSZ);
  float mean = sums[o] * invN;
  float var = sumsq[o] * invN - mean * mean;
  float rstd = rsqrtf(var + EPS);
  float g = gamma[o] * rstd;
  float bta = beta[o] - mean * g;
  float4 v = ((const float4*)ybuf)[gid];
  float4 r;
  r.x = fmaxf(v.x * g + bta, 0.0f);
  r.y = fmaxf(v.y * g + bta, 0.0f);
  r.z = fmaxf(v.z * g + bta, 0.0f);
  r.w = fmaxf(v.w * g + bta, 0.0f);
  ((float4*)out)[gid] = r;
}

extern "C" void kernel_launch(void* const* d_in, const int* in_sizes, int n_in,
                              void* d_out, int out_size, void* d_ws, size_t ws_size,
                              hipStream_t stream) {
  const float* x     = (const float*)d_in[0];
  const float* off_w = (const float*)d_in[1];
  const float* off_b = (const float*)d_in[2];
  const float* dc_w  = (const float*)d_in[3];
  const float* dc_b  = (const float*)d_in[4];
  const float* gamma = (const float*)d_in[5];
  const float* beta  = (const float*)d_in[6];
  float* ws = (float*)d_ws;
  int*   Bg    = (int*)(ws + WS_BG);
  int*   Bgo   = (int*)(ws + WS_BGO);
  float* sums  = ws + WS_SUMS;
  float* sumsq = ws + WS_SUMSQ;
  float* ybuf  = ws + WS_YBUF;
  float* out = (float*)d_out;
  unsigned int* xTu = (unsigned int*)d_out;  // d_out doubles as NHWC-bf16 scratch

  int nb = 0;
  hipError_t qe = hipOccupancyMaxActiveBlocksPerMultiprocessor(
      &nb, reinterpret_cast<const void*>(coop_kernel), 256, 0);
  bool coop_ok = (qe == hipSuccess) && (nb >= 4);

  if (coop_ok) {
    void* args[] = {(void*)&x, (void*)&off_w, (void*)&dc_w, (void*)&off_b,
                    (void*)&dc_b, (void*)&gamma, (void*)&beta, (void*)&xTu,
                    (void*)&Bg, (void*)&Bgo, (void*)&sums, (void*)&sumsq,
                    (void*)&out};
    hipError_t le = hipLaunchCooperativeKernel(
        reinterpret_cast<const void*>(coop_kernel), dim3(BB * HWSZ / 64),
        dim3(256), args, 0, stream);
    if (le == hipSuccess) return;
  }
  // fallback: 3-launch pipeline
  prep_kernel<<<BB * HH + 64, 256, 0, stream>>>(x, off_w, dc_w, xTu, Bg, Bgo, sums);
  conv_kernel<<<BB * HWSZ / 64, 256, 0, stream>>>(xTu, Bg, Bgo, off_b, dc_b, ybuf, sums, sumsq);
  norm_kernel<<<BB * OO * HWSZ / (4 * 256), 256, 0, stream>>>(ybuf, sums, sumsq, gamma, beta, out);
}